// Round 10
// baseline (3787.231 us; speedup 1.0000x reference)
//
#include <hip/hip_runtime.h>
#include <hip/hip_bf16.h>
#include <math.h>

typedef __attribute__((ext_vector_type(4))) short short4v;
typedef __attribute__((ext_vector_type(8))) short short8;
typedef __attribute__((ext_vector_type(4))) float f32x4;

#define BATCH   4096
#define XLEN    1008
#define NOC1    128
#define NPOS    32
#define NOC2    256
#define NQ      9
#define NCAPS   288
#define NDIM    8

// ws layout (bytes)
#define BWH_OFF   0           // wavelet B-pack hi bf16, 128 KB
#define BWL_OFF   131072      // wavelet B-pack lo bf16, 128 KB
#define BPH_OFF   262144      // conv2 B-pack hi bf16, 1 MB
#define BPL_OFF   1310720     // conv2 B-pack lo bf16, 1 MB
#define H2HI_OFF  2359296     // h2 hi bf16 [b][pos32][ic128], 33.55 MB
#define H2LO_OFF  35913728    // h2 lo bf16, 33.55 MB
#define U_OFF     69468160    // u fp32 [b][288][8], 37.75 MB

struct HL { short hi, lo; };

static __device__ inline HL split2(float v) {
    HL r;
    __hip_bfloat16 h = __float2bfloat16(v);
    r.hi = *reinterpret_cast<short*>(&h);
    float rem = v - __bfloat162float(h);
    __hip_bfloat16 l = __float2bfloat16(rem);
    r.lo = *reinterpret_cast<short*>(&l);
    return r;
}

// DPP 16-lane (row) sum — VALU pipe, no LDS. Bitwise == shfl_xor 1/2/4/8 tree.
template <int CTRL>
static __device__ __forceinline__ float dpp_addf(float x) {
    int y = __builtin_amdgcn_update_dpp(0, __builtin_bit_cast(int, x),
                                        CTRL, 0xf, 0xf, true);
    return x + __builtin_bit_cast(float, y);
}
static __device__ __forceinline__ float rowsum16(float x) {
    x = dpp_addf<0xB1>(x);    // quad_perm xor1
    x = dpp_addf<0x4E>(x);    // quad_perm xor2
    x = dpp_addf<0x141>(x);   // row_half_mirror
    x = dpp_addf<0x140>(x);   // row_mirror
    return x;
}

// ---------------- K1a: wavelet weights directly in MFMA B-fragment order ---
__global__ __launch_bounds__(256) void k_wav_pack(const float* __restrict__ a,
                                                  const float* __restrict__ w,
                                                  __hip_bfloat16* __restrict__ bh,
                                                  __hip_bfloat16* __restrict__ bl) {
    int idx = blockIdx.x * 256 + threadIdx.x;   // 65536 total
    int e    = idx & 7;
    int lane = (idx >> 3) & 63;
    int s    = (idx >> 9) & 15;
    int nt   = idx >> 13;
    int oc = nt * 16 + (lane & 15);
    int k  = s * 32 + (lane >> 4) * 8 + e;
    float t  = -1.0f + 2.0f * (float)k / 511.0f;
    float av = fmaxf(a[oc], 1e-5f);
    float ts = t / av;
    float v = cosf(w[oc] * t) * expf(-0.5f * ts * ts);
    HL r = split2(v);
    ((short*)bh)[idx] = r.hi;
    ((short*)bl)[idx] = r.lo;
}

// ---------------- K1b: pack conv_w into MFMA B-fragment order, bf16 hi/lo --
__global__ __launch_bounds__(256) void k_pack_b(const float* __restrict__ cw,
                                                __hip_bfloat16* __restrict__ bh,
                                                __hip_bfloat16* __restrict__ bl) {
    int o = blockIdx.x * 256 + threadIdx.x;   // 524288 total
    int e    = o & 7;
    int lane = (o >> 3) & 63;
    int s    = (o >> 9) & 63;
    int nt   = o >> 15;
    int n  = nt * 16 + (lane & 15);
    int j  = lane >> 4;
    int kk = s >> 2;
    int ic = (s & 3) * 32 + j * 8 + e;
    float v = cw[(n * NOC1 + ic) * 16 + kk];
    HL r = split2(v);
    ((short*)bh)[o] = r.hi;
    ((short*)bl)[o] = r.lo;
}

// ---------------- K2: WavConv via bf16 MFMA (3-term split) -----------------
__global__ __launch_bounds__(256, 2) void k_wavconv_mfma(
        const float* __restrict__ x,
        const __hip_bfloat16* __restrict__ bwh,
        const __hip_bfloat16* __restrict__ bwl,
        __hip_bfloat16* __restrict__ h2hi,
        __hip_bfloat16* __restrict__ h2lo) {
    __shared__ short xl[2][8][1512];   // 48384 B; slot(i) = i + 8*(i>>4)

    int tid = threadIdx.x;
    int b0  = blockIdx.x * 8;

    for (int i4 = tid; i4 < 2016; i4 += 256) {
        int b  = i4 / 252;
        int e4 = i4 - b * 252;
        float4 v = *(const float4*)(x + (size_t)(b0 + b) * XLEN + e4 * 4);
        int i    = e4 * 4;
        int slot = i + 8 * (i >> 4);
        HL r0 = split2(v.x);
        HL r1 = split2(v.y);
        HL r2 = split2(v.z);
        HL r3 = split2(v.w);
        short4v hv, lv;
        hv.x = r0.hi; hv.y = r1.hi; hv.z = r2.hi; hv.w = r3.hi;
        lv.x = r0.lo; lv.y = r1.lo; lv.z = r2.lo; lv.w = r3.lo;
        *(short4v*)&xl[0][b][slot] = hv;
        *(short4v*)&xl[1][b][slot] = lv;
    }
    __syncthreads();

    int lane = tid & 63;
    int w    = tid >> 6;     // 0..3
    int col  = lane & 15;
    int rg   = lane >> 4;    // 0..3

    f32x4 acc[4][8];
    f32x4 z = {0.f, 0.f, 0.f, 0.f};
#pragma unroll
    for (int tl = 0; tl < 4; ++tl)
#pragma unroll
        for (int nt = 0; nt < 8; ++nt) acc[tl][nt] = z;

    for (int s = 0; s < 16; ++s) {
        short8 Bh[8], Bl[8];
#pragma unroll
        for (int nt = 0; nt < 8; ++nt) {
            size_t off = ((size_t)(nt * 16 + s) * 64 + lane) * 8;
            Bh[nt] = *(const short8*)(bwh + off);
            Bl[nt] = *(const short8*)(bwl + off);
        }
#pragma unroll
        for (int tl = 0; tl < 4; ++tl) {
            int mt  = 4 * w + tl;
            int bl  = mt >> 1;
            int pos = (mt & 1) * 16 + col;
            int i    = (pos + 2 * s) * 16 + rg * 8;
            int slot = i + 8 * (i >> 4);
            short8 ah = *(const short8*)&xl[0][bl][slot];
            short8 al = *(const short8*)&xl[1][bl][slot];
#pragma unroll
            for (int nt = 0; nt < 8; ++nt) {
                acc[tl][nt] = __builtin_amdgcn_mfma_f32_16x16x32_bf16(ah, Bh[nt], acc[tl][nt], 0, 0, 0);
                acc[tl][nt] = __builtin_amdgcn_mfma_f32_16x16x32_bf16(ah, Bl[nt], acc[tl][nt], 0, 0, 0);
                acc[tl][nt] = __builtin_amdgcn_mfma_f32_16x16x32_bf16(al, Bh[nt], acc[tl][nt], 0, 0, 0);
            }
        }
    }

#pragma unroll
    for (int tl = 0; tl < 4; ++tl) {
        int mt = 4 * w + tl;
        int b  = b0 + (mt >> 1);
        int ph = (mt & 1) * 16;
#pragma unroll
        for (int nt = 0; nt < 8; ++nt) {
            int oc = nt * 16 + col;
#pragma unroll
            for (int r = 0; r < 4; ++r) {
                int pos = ph + rg * 4 + r;
                size_t off = ((size_t)b * NPOS + pos) * NOC1 + oc;
                HL rr = split2(acc[tl][nt][r]);
                ((short*)h2hi)[off] = rr.hi;
                ((short*)h2lo)[off] = rr.lo;
            }
        }
    }
}

// ---------------- K3: PrimaryCaps conv via bf16 MFMA + squash --------------
// 8 batches/block, grid 512 (2 blocks/CU), 512 threads.
// Software-pipelined: A double-buffered in LDS (stage t+1 overlaps MFMA t,
// ONE barrier per step), B prefetched one step ahead into registers.
// Math identical to r9 (same summation order) -> absmax unchanged.
__global__ __launch_bounds__(512, 4) void k_conv_mfma(const __hip_bfloat16* __restrict__ h2hi,
                                                      const __hip_bfloat16* __restrict__ h2lo,
                                                      const __hip_bfloat16* __restrict__ bph,
                                                      const __hip_bfloat16* __restrict__ bpl,
                                                      const float* __restrict__ cb,
                                                      float* __restrict__ u) {
    __shared__ char smem[46080];     // 2 A-buffers (23040 B each); epilogue p_lds
    short* Abuf[2];
    Abuf[0] = (short*)smem;
    Abuf[1] = (short*)(smem + 23040);
    float* p_lds = (float*)smem;     // [8 b][1152] (36864 B, fits)

    int tid  = threadIdx.x;
    int w    = tid >> 6;
    int lane = tid & 63;
    int col  = lane & 15;
    int rg   = lane >> 4;
    int b0   = blockIdx.x * 8;

    f32x4 acc[5][2];
    f32x4 z = {0.f, 0.f, 0.f, 0.f};
#pragma unroll
    for (int mt = 0; mt < 5; ++mt) { acc[mt][0] = z; acc[mt][1] = z; }

    // precompute this thread's stage indices (up to 3 rows)
    // stage(t, buf): 2v x 72 rows x 64 shorts
    auto stageA = [&](int t, short* dst) {
        int kk = t >> 1;
        int hb = (t & 1) * 64;
#pragma unroll
        for (int k3 = 0; k3 < 3; ++k3) {
            int idx = tid + k3 * 512;
            if (idx < 1152) {
                int m  = idx % 72;
                int r2 = idx / 72;          // 0..15
                int g  = r2 & 7;
                int v  = r2 >> 3;
                const __hip_bfloat16* src = (v ? h2lo : h2hi) +
                    ((size_t)(b0 + (m & 7)) * NPOS + (2 * (m >> 3) + kk)) * NOC1 + hb + g * 8;
                *(short8*)&dst[v * 5760 + m * 72 + g * 8] = *(const short8*)src;
            }
        }
    };

    // B regs: [phase][n*2+j] hi/lo
    short8 Bh[2][4], Bl[2][4];
    auto loadB = [&](int t, int ph) {
        int kk = t >> 1;
        int sbase = kk * 4 + (t & 1) * 2;
#pragma unroll
        for (int n = 0; n < 2; ++n) {
            int nt = w + n * 8;
#pragma unroll
            for (int j = 0; j < 2; ++j) {
                size_t bo = ((size_t)(nt * 64 + sbase + j) * 64 + lane) * 8;
                Bh[ph][n * 2 + j] = *(const short8*)(bph + bo);
                Bl[ph][n * 2 + j] = *(const short8*)(bpl + bo);
            }
        }
    };

    stageA(0, Abuf[0]);
    loadB(0, 0);
    __syncthreads();

    for (int t = 0; t < 32; ++t) {
        int cur = t & 1;
        if (t < 31) {
            stageA(t + 1, Abuf[1 - cur]);   // disjoint buffer — no barrier needed yet
            loadB(t + 1, 1 - cur);
        }
        short* A = Abuf[cur];
#pragma unroll
        for (int j = 0; j < 2; ++j)
#pragma unroll
            for (int mt = 0; mt < 5; ++mt) {
                int aoff = (mt * 16 + col) * 72 + j * 32 + rg * 8;
                short8 ah = *(const short8*)&A[aoff];
                short8 al = *(const short8*)&A[5760 + aoff];
#pragma unroll
                for (int n = 0; n < 2; ++n) {
                    acc[mt][n] = __builtin_amdgcn_mfma_f32_16x16x32_bf16(ah, Bh[cur][n * 2 + j], acc[mt][n], 0, 0, 0);
                    acc[mt][n] = __builtin_amdgcn_mfma_f32_16x16x32_bf16(ah, Bl[cur][n * 2 + j], acc[mt][n], 0, 0, 0);
                    acc[mt][n] = __builtin_amdgcn_mfma_f32_16x16x32_bf16(al, Bh[cur][n * 2 + j], acc[mt][n], 0, 0, 0);
                }
            }
        __syncthreads();   // stage(t+1) writes done; MFMA(t) reads done
    }

    // Epilogue per 128-oc2 chunk. C/D: col = n within tile, row = rg*4 + r.
    for (int ch = 0; ch < 2; ++ch) {
        int oc2l = w * 16 + col;                // chunk-local oc2 (tile ch*8+w)
        float bias = cb[ch * 128 + oc2l];
#pragma unroll
        for (int mt = 0; mt < 5; ++mt)
#pragma unroll
            for (int r = 0; r < 4; ++r) {
                int m = mt * 16 + rg * 4 + r;
                if (m < 72) {
                    int q = m >> 3;
                    int b = m & 7;
                    p_lds[b * 1152 + oc2l * 9 + q] = acc[mt][ch][r] + bias;
                }
            }
        __syncthreads();
        for (int idx = tid; idx < 1152; idx += 512) {   // 8 b x 144 caps
            int b  = idx / 144;
            int cl = idx - b * 144;
            float* pp = &p_lds[b * 1152 + cl * 8];
            float sn = 0.f;
#pragma unroll
            for (int i = 0; i < NDIM; ++i) sn = fmaf(pp[i], pp[i], sn);
            float sc = sn / (1.f + sn) / sqrtf(sn + 1e-8f);
            float* ug = u + ((size_t)(b0 + b) * (NCAPS * NDIM) + (ch * 144 + cl) * 8);
            float4 u0 = make_float4(pp[0] * sc, pp[1] * sc, pp[2] * sc, pp[3] * sc);
            float4 u1 = make_float4(pp[4] * sc, pp[5] * sc, pp[6] * sc, pp[7] * sc);
            ((float4*)ug)[0] = u0;
            ((float4*)ug)[1] = u1;
        }
        __syncthreads();
    }
}

// ---------------- K4: u_hat + routing, 2 batches/block, 512 threads --------
__global__ __launch_bounds__(512, 4) void k_routing(const float* __restrict__ u,
                                                    const float* __restrict__ Wc,
                                                    float* __restrict__ out) {
    __shared__ float b_lds[2][NCAPS * 4];     // 9216 B
    __shared__ float c_lds[2][NCAPS * 4];     // 9216 B
    __shared__ float part_lds[2][512];        // 4096 B
    __shared__ float v_lds[2][64];            // 512 B

    int tid = threadIdx.x;
    int b0  = blockIdx.x * 2;

    int g = tid >> 6;
    int l = tid & 63;
    int d = l >> 4;
    int o = l & 15;
    int gu = __builtin_amdgcn_readfirstlane(g);   // wave-uniform -> s_load for u

    const float* ub0 = u + (size_t)(b0 + 0) * (NCAPS * NDIM) + gu * 36 * NDIM;
    const float* ub1 = u + (size_t)(b0 + 1) * (NCAPS * NDIM) + gu * 36 * NDIM;

    float uh0[36], uh1[36];
#pragma unroll
    for (int c = 0; c < 36; ++c) {
        int cap = gu * 36 + c;
        const float4* W4 = (const float4*)(Wc + ((size_t)cap * 512) + l * 8);
        float4 A  = W4[0];
        float4 Bv = W4[1];
        float t0 = A.x * ub0[c * 8 + 0];
        t0 = fmaf(A.y,  ub0[c * 8 + 1], t0);
        t0 = fmaf(A.z,  ub0[c * 8 + 2], t0);
        t0 = fmaf(A.w,  ub0[c * 8 + 3], t0);
        t0 = fmaf(Bv.x, ub0[c * 8 + 4], t0);
        t0 = fmaf(Bv.y, ub0[c * 8 + 5], t0);
        t0 = fmaf(Bv.z, ub0[c * 8 + 6], t0);
        t0 = fmaf(Bv.w, ub0[c * 8 + 7], t0);
        uh0[c] = t0;
        float t1 = A.x * ub1[c * 8 + 0];
        t1 = fmaf(A.y,  ub1[c * 8 + 1], t1);
        t1 = fmaf(A.z,  ub1[c * 8 + 2], t1);
        t1 = fmaf(A.w,  ub1[c * 8 + 3], t1);
        t1 = fmaf(Bv.x, ub1[c * 8 + 4], t1);
        t1 = fmaf(Bv.y, ub1[c * 8 + 5], t1);
        t1 = fmaf(Bv.z, ub1[c * 8 + 6], t1);
        t1 = fmaf(Bv.w, ub1[c * 8 + 7], t1);
        uh1[c] = t1;
    }

    for (int r = 0; r < 3; ++r) {
        if (r > 0) {
            __builtin_amdgcn_wave_barrier();
            for (int i = l; i < 72; i += 64) {
                int bb = (i >= 36) ? 1 : 0;
                int cl = i - bb * 36;
                int c  = gu * 36 + cl;
                float4 bv = *(const float4*)&b_lds[bb][c * 4];
                float m  = fmaxf(fmaxf(bv.x, bv.y), fmaxf(bv.z, bv.w));
                float e0 = expf(bv.x - m), e1 = expf(bv.y - m);
                float e2 = expf(bv.z - m), e3 = expf(bv.w - m);
                float inv = 1.f / (e0 + e1 + e2 + e3);
                e0 *= inv; e1 *= inv; e2 *= inv; e3 *= inv;
                *(float4*)&c_lds[bb][c * 4] = make_float4(e0, e1, e2, e3);
                if (r == 2) {
                    *(float4*)(out + 16384 + ((size_t)(b0 + bb) * NCAPS + c) * 4) =
                        make_float4(e0, e1, e2, e3);
                }
            }
            __builtin_amdgcn_wave_barrier();
        }

        float p0 = 0.f, p1 = 0.f;
        if (r == 0) {
#pragma unroll
            for (int c = 0; c < 36; ++c) {
                p0 = fmaf(0.25f, uh0[c], p0);
                p1 = fmaf(0.25f, uh1[c], p1);
            }
        } else {
#pragma unroll
            for (int c = 0; c < 36; ++c) {
                p0 = fmaf(c_lds[0][(g * 36 + c) * 4 + d], uh0[c], p0);
                p1 = fmaf(c_lds[1][(g * 36 + c) * 4 + d], uh1[c], p1);
            }
        }
        part_lds[0][tid] = p0;
        part_lds[1][tid] = p1;
        __syncthreads();

        if (tid < 128) {
            int bb = tid >> 6;
            int ll = tid & 63;
            float sv = 0.f;
#pragma unroll
            for (int k = 0; k < 8; ++k) sv += part_lds[bb][ll + 64 * k];
            float sq = rowsum16(sv * sv);
            float sc = sq / (1.f + sq) / sqrtf(sq + 1e-8f);
            float v  = sv * sc;
            v_lds[bb][ll] = v;
            if (r == 2) {
                float vv = rowsum16(v * v);
                if ((ll & 15) == 0)
                    out[(size_t)(b0 + bb) * 4 + (ll >> 4)] = sqrtf(vv);
            }
        }
        __syncthreads();

        if (r < 2) {
            float v0 = v_lds[0][l];
            float v1 = v_lds[1][l];
#pragma unroll
            for (int c = 0; c < 36; ++c) {
                float t0 = rowsum16(uh0[c] * v0);
                float t1 = rowsum16(uh1[c] * v1);
                if (o == 0) {
                    if (r == 0) {
                        b_lds[0][(g * 36 + c) * 4 + d] = t0;
                        b_lds[1][(g * 36 + c) * 4 + d] = t1;
                    } else {
                        b_lds[0][(g * 36 + c) * 4 + d] += t0;
                        b_lds[1][(g * 36 + c) * 4 + d] += t1;
                    }
                }
            }
        }
    }
}

extern "C" void kernel_launch(void* const* d_in, const int* in_sizes, int n_in,
                              void* d_out, int out_size, void* d_ws, size_t ws_size,
                              hipStream_t stream) {
    const float* x      = (const float*)d_in[0];
    const float* a      = (const float*)d_in[1];
    const float* w      = (const float*)d_in[2];
    const float* conv_w = (const float*)d_in[3];
    const float* conv_b = (const float*)d_in[4];
    const float* W_caps = (const float*)d_in[5];
    float* out = (float*)d_out;
    char* ws   = (char*)d_ws;

    __hip_bfloat16*  bwh  = (__hip_bfloat16*)(ws + BWH_OFF);
    __hip_bfloat16*  bwl  = (__hip_bfloat16*)(ws + BWL_OFF);
    __hip_bfloat16*  bph  = (__hip_bfloat16*)(ws + BPH_OFF);
    __hip_bfloat16*  bpl  = (__hip_bfloat16*)(ws + BPL_OFF);
    __hip_bfloat16*  h2hi = (__hip_bfloat16*)(ws + H2HI_OFF);
    __hip_bfloat16*  h2lo = (__hip_bfloat16*)(ws + H2LO_OFF);
    float*           u    = (float*)(ws + U_OFF);

    k_wav_pack<<<256, 256, 0, stream>>>(a, w, bwh, bwl);
    k_pack_b<<<2048, 256, 0, stream>>>(conv_w, bph, bpl);
    k_wavconv_mfma<<<BATCH / 8, 256, 0, stream>>>(x, bwh, bwl, h2hi, h2lo);
    k_conv_mfma<<<BATCH / 8, 512, 0, stream>>>(h2hi, h2lo, bph, bpl, conv_b, u);
    k_routing<<<BATCH / 2, 512, 0, stream>>>(u, W_caps, out);
}

// Round 11
// 347.586 us; speedup vs baseline: 10.8958x; 10.8958x over previous
//
#include <hip/hip_runtime.h>
#include <hip/hip_bf16.h>
#include <math.h>

typedef __attribute__((ext_vector_type(4))) short short4v;
typedef __attribute__((ext_vector_type(8))) short short8;
typedef __attribute__((ext_vector_type(4))) float f32x4;

#define BATCH   4096
#define XLEN    1008
#define NOC1    128
#define NPOS    32
#define NOC2    256
#define NQ      9
#define NCAPS   288
#define NDIM    8

// ws layout (bytes)
#define BWH_OFF   0           // wavelet B-pack hi bf16, 128 KB
#define BWL_OFF   131072      // wavelet B-pack lo bf16, 128 KB
#define BPH_OFF   262144      // conv2 B-pack hi bf16, 1 MB
#define BPL_OFF   1310720     // conv2 B-pack lo bf16, 1 MB
#define H2HI_OFF  2359296     // h2 hi bf16 [b][pos32][ic128], 33.55 MB
#define H2LO_OFF  35913728    // h2 lo bf16, 33.55 MB
#define U_OFF     69468160    // u fp32 [b][288][8], 37.75 MB

struct HL { short hi, lo; };

static __device__ inline HL split2(float v) {
    HL r;
    __hip_bfloat16 h = __float2bfloat16(v);
    r.hi = *reinterpret_cast<short*>(&h);
    float rem = v - __bfloat162float(h);
    __hip_bfloat16 l = __float2bfloat16(rem);
    r.lo = *reinterpret_cast<short*>(&l);
    return r;
}

// DPP 16-lane (row) sum — VALU pipe, no LDS. Bitwise == shfl_xor 1/2/4/8 tree.
template <int CTRL>
static __device__ __forceinline__ float dpp_addf(float x) {
    int y = __builtin_amdgcn_update_dpp(0, __builtin_bit_cast(int, x),
                                        CTRL, 0xf, 0xf, true);
    return x + __builtin_bit_cast(float, y);
}
static __device__ __forceinline__ float rowsum16(float x) {
    x = dpp_addf<0xB1>(x);    // quad_perm xor1
    x = dpp_addf<0x4E>(x);    // quad_perm xor2
    x = dpp_addf<0x141>(x);   // row_half_mirror
    x = dpp_addf<0x140>(x);   // row_mirror
    return x;
}

// ---------------- K1a: wavelet weights directly in MFMA B-fragment order ---
__global__ __launch_bounds__(256) void k_wav_pack(const float* __restrict__ a,
                                                  const float* __restrict__ w,
                                                  __hip_bfloat16* __restrict__ bh,
                                                  __hip_bfloat16* __restrict__ bl) {
    int idx = blockIdx.x * 256 + threadIdx.x;   // 65536 total
    int e    = idx & 7;
    int lane = (idx >> 3) & 63;
    int s    = (idx >> 9) & 15;
    int nt   = idx >> 13;
    int oc = nt * 16 + (lane & 15);
    int k  = s * 32 + (lane >> 4) * 8 + e;
    float t  = -1.0f + 2.0f * (float)k / 511.0f;
    float av = fmaxf(a[oc], 1e-5f);
    float ts = t / av;
    float v = cosf(w[oc] * t) * expf(-0.5f * ts * ts);
    HL r = split2(v);
    ((short*)bh)[idx] = r.hi;
    ((short*)bl)[idx] = r.lo;
}

// ---------------- K1b: pack conv_w into MFMA B-fragment order, bf16 hi/lo --
__global__ __launch_bounds__(256) void k_pack_b(const float* __restrict__ cw,
                                                __hip_bfloat16* __restrict__ bh,
                                                __hip_bfloat16* __restrict__ bl) {
    int o = blockIdx.x * 256 + threadIdx.x;   // 524288 total
    int e    = o & 7;
    int lane = (o >> 3) & 63;
    int s    = (o >> 9) & 63;
    int nt   = o >> 15;
    int n  = nt * 16 + (lane & 15);
    int j  = lane >> 4;
    int kk = s >> 2;
    int ic = (s & 3) * 32 + j * 8 + e;
    float v = cw[(n * NOC1 + ic) * 16 + kk];
    HL r = split2(v);
    ((short*)bh)[o] = r.hi;
    ((short*)bl)[o] = r.lo;
}

// ---------------- K2: WavConv via bf16 MFMA (3-term split) -----------------
__global__ __launch_bounds__(256, 2) void k_wavconv_mfma(
        const float* __restrict__ x,
        const __hip_bfloat16* __restrict__ bwh,
        const __hip_bfloat16* __restrict__ bwl,
        __hip_bfloat16* __restrict__ h2hi,
        __hip_bfloat16* __restrict__ h2lo) {
    __shared__ short xl[2][8][1512];   // 48384 B; slot(i) = i + 8*(i>>4)

    int tid = threadIdx.x;
    int b0  = blockIdx.x * 8;

    for (int i4 = tid; i4 < 2016; i4 += 256) {
        int b  = i4 / 252;
        int e4 = i4 - b * 252;
        float4 v = *(const float4*)(x + (size_t)(b0 + b) * XLEN + e4 * 4);
        int i    = e4 * 4;
        int slot = i + 8 * (i >> 4);
        HL r0 = split2(v.x);
        HL r1 = split2(v.y);
        HL r2 = split2(v.z);
        HL r3 = split2(v.w);
        short4v hv, lv;
        hv.x = r0.hi; hv.y = r1.hi; hv.z = r2.hi; hv.w = r3.hi;
        lv.x = r0.lo; lv.y = r1.lo; lv.z = r2.lo; lv.w = r3.lo;
        *(short4v*)&xl[0][b][slot] = hv;
        *(short4v*)&xl[1][b][slot] = lv;
    }
    __syncthreads();

    int lane = tid & 63;
    int w    = tid >> 6;     // 0..3
    int col  = lane & 15;
    int rg   = lane >> 4;    // 0..3

    f32x4 acc[4][8];
    f32x4 z = {0.f, 0.f, 0.f, 0.f};
#pragma unroll
    for (int tl = 0; tl < 4; ++tl)
#pragma unroll
        for (int nt = 0; nt < 8; ++nt) acc[tl][nt] = z;

    for (int s = 0; s < 16; ++s) {
        short8 Bh[8], Bl[8];
#pragma unroll
        for (int nt = 0; nt < 8; ++nt) {
            size_t off = ((size_t)(nt * 16 + s) * 64 + lane) * 8;
            Bh[nt] = *(const short8*)(bwh + off);
            Bl[nt] = *(const short8*)(bwl + off);
        }
#pragma unroll
        for (int tl = 0; tl < 4; ++tl) {
            int mt  = 4 * w + tl;
            int bl  = mt >> 1;
            int pos = (mt & 1) * 16 + col;
            int i    = (pos + 2 * s) * 16 + rg * 8;
            int slot = i + 8 * (i >> 4);
            short8 ah = *(const short8*)&xl[0][bl][slot];
            short8 al = *(const short8*)&xl[1][bl][slot];
#pragma unroll
            for (int nt = 0; nt < 8; ++nt) {
                acc[tl][nt] = __builtin_amdgcn_mfma_f32_16x16x32_bf16(ah, Bh[nt], acc[tl][nt], 0, 0, 0);
                acc[tl][nt] = __builtin_amdgcn_mfma_f32_16x16x32_bf16(ah, Bl[nt], acc[tl][nt], 0, 0, 0);
                acc[tl][nt] = __builtin_amdgcn_mfma_f32_16x16x32_bf16(al, Bh[nt], acc[tl][nt], 0, 0, 0);
            }
        }
    }

#pragma unroll
    for (int tl = 0; tl < 4; ++tl) {
        int mt = 4 * w + tl;
        int b  = b0 + (mt >> 1);
        int ph = (mt & 1) * 16;
#pragma unroll
        for (int nt = 0; nt < 8; ++nt) {
            int oc = nt * 16 + col;
#pragma unroll
            for (int r = 0; r < 4; ++r) {
                int pos = ph + rg * 4 + r;
                size_t off = ((size_t)b * NPOS + pos) * NOC1 + oc;
                HL rr = split2(acc[tl][nt][r]);
                ((short*)h2hi)[off] = rr.hi;
                ((short*)h2lo)[off] = rr.lo;
            }
        }
    }
}

// ---------------- K3: PrimaryCaps conv via bf16 MFMA + squash --------------
// Grid 512 = 256 batch-groups x 2 N-halves. Block: 16 batches x 128 oc2.
// 8 waves; wave w owns global n-tile ch*8+w. M = 144 rows (tile mt=q, row=b).
// BK=32, 64 steps, A double-buffered with COMPILE-TIME buffer alternation
// (2x-unrolled loop) -> 1 barrier/step, staging overlaps MFMA.
// Summation order = r9 (s sequential, hh/hl/lh) -> bit-identical results.
__global__ __launch_bounds__(512, 5) void k_conv_mfma(const __hip_bfloat16* __restrict__ h2hi,
                                                      const __hip_bfloat16* __restrict__ h2lo,
                                                      const __hip_bfloat16* __restrict__ bph,
                                                      const __hip_bfloat16* __restrict__ bpl,
                                                      const float* __restrict__ cb,
                                                      float* __restrict__ u) {
    __shared__ char smem[46080];         // 2 A-buffers (23040 B); epilogue p_lds
    short* A0 = (short*)smem;            // [2 v][144 m][stride 40]
    short* A1 = (short*)(smem + 23040);
    float* p_lds = (float*)smem;         // [8 b][1152] (36864 B)

    int tid  = threadIdx.x;
    int w    = tid >> 6;
    int lane = tid & 63;
    int col  = lane & 15;
    int rg   = lane >> 4;
    int bg   = blockIdx.x >> 1;
    int ch   = blockIdx.x & 1;
    int b0   = bg * 16;
    int nt   = ch * 8 + w;               // this wave's global n-tile

    f32x4 acc[9];
    f32x4 z = {0.f, 0.f, 0.f, 0.f};
#pragma unroll
    for (int mt = 0; mt < 9; ++mt) acc[mt] = z;

    // stage step s into dst: 2v x 144 rows x 32 shorts (4 b128 chunks/row)
    auto stageA = [&](int s, short* dst) {
        int kk  = s >> 2;
        int icb = (s & 3) * 32;
#pragma unroll
        for (int k3 = 0; k3 < 3; ++k3) {
            int idx = tid + k3 * 512;
            if (idx < 1152) {
                int v  = idx >= 576;
                int j2 = idx - v * 576;
                int m  = j2 >> 2;        // 0..143: b = m&15, q = m>>4
                int g  = j2 & 3;
                const __hip_bfloat16* src = (v ? h2lo : h2hi) +
                    ((size_t)(b0 + (m & 15)) * NPOS + (2 * (m >> 4) + kk)) * NOC1 + icb + g * 8;
                *(short8*)&dst[v * 5760 + m * 40 + g * 8] = *(const short8*)src;
            }
        }
    };

    auto mfmaStep = [&](int s, const short* A) {
        size_t bo = ((size_t)(nt * 64 + s) * 64 + lane) * 8;
        short8 Bh = *(const short8*)(bph + bo);
        short8 Bl = *(const short8*)(bpl + bo);
#pragma unroll
        for (int mt = 0; mt < 9; ++mt) {
            int aoff = (mt * 16 + col) * 40 + rg * 8;
            short8 ah = *(const short8*)&A[aoff];
            short8 al = *(const short8*)&A[5760 + aoff];
            acc[mt] = __builtin_amdgcn_mfma_f32_16x16x32_bf16(ah, Bh, acc[mt], 0, 0, 0);
            acc[mt] = __builtin_amdgcn_mfma_f32_16x16x32_bf16(ah, Bl, acc[mt], 0, 0, 0);
            acc[mt] = __builtin_amdgcn_mfma_f32_16x16x32_bf16(al, Bh, acc[mt], 0, 0, 0);
        }
    };

    stageA(0, A0);
    __syncthreads();
    for (int s = 0; s < 64; s += 2) {
        if (s + 1 < 64) stageA(s + 1, A1);   // other buffer: no race with reads of A0
        mfmaStep(s, A0);
        __syncthreads();                      // A1 writes visible; A0 reads done
        if (s + 2 < 64) stageA(s + 2, A0);
        mfmaStep(s + 1, A1);
        __syncthreads();
    }

    // Epilogue in two 8-batch passes. C/D: n = col, mrow = rg*4+r = batch.
    int oc2l = w * 16 + col;                  // chunk-local oc2 (0..127)
    float bias = cb[ch * 128 + oc2l];
    for (int pp = 0; pp < 2; ++pp) {
#pragma unroll
        for (int mt = 0; mt < 9; ++mt)
#pragma unroll
            for (int r = 0; r < 4; ++r) {
                int b = rg * 4 + r;           // 0..15
                if ((b >> 3) == pp)
                    p_lds[(b & 7) * 1152 + oc2l * 9 + mt] = acc[mt][r] + bias;
            }
        __syncthreads();
        for (int idx = tid; idx < 1152; idx += 512) {   // 8 b x 144 caps
            int lb = idx / 144;
            int cl = idx - lb * 144;
            float* ppt = &p_lds[lb * 1152 + cl * 8];
            float sn = 0.f;
#pragma unroll
            for (int i = 0; i < NDIM; ++i) sn = fmaf(ppt[i], ppt[i], sn);
            float sc = sn / (1.f + sn) / sqrtf(sn + 1e-8f);
            float* ug = u + ((size_t)(b0 + pp * 8 + lb) * (NCAPS * NDIM) +
                             (ch * 144 + cl) * 8);
            float4 u0 = make_float4(ppt[0] * sc, ppt[1] * sc, ppt[2] * sc, ppt[3] * sc);
            float4 u1 = make_float4(ppt[4] * sc, ppt[5] * sc, ppt[6] * sc, ppt[7] * sc);
            ((float4*)ug)[0] = u0;
            ((float4*)ug)[1] = u1;
        }
        __syncthreads();
    }
}

// ---------------- K4: u_hat + routing, 2 batches/block, 512 threads --------
__global__ __launch_bounds__(512, 4) void k_routing(const float* __restrict__ u,
                                                    const float* __restrict__ Wc,
                                                    float* __restrict__ out) {
    __shared__ float b_lds[2][NCAPS * 4];     // 9216 B
    __shared__ float c_lds[2][NCAPS * 4];     // 9216 B
    __shared__ float part_lds[2][512];        // 4096 B
    __shared__ float v_lds[2][64];            // 512 B

    int tid = threadIdx.x;
    int b0  = blockIdx.x * 2;

    int g = tid >> 6;
    int l = tid & 63;
    int d = l >> 4;
    int o = l & 15;
    int gu = __builtin_amdgcn_readfirstlane(g);   // wave-uniform -> s_load for u

    const float* ub0 = u + (size_t)(b0 + 0) * (NCAPS * NDIM) + gu * 36 * NDIM;
    const float* ub1 = u + (size_t)(b0 + 1) * (NCAPS * NDIM) + gu * 36 * NDIM;

    float uh0[36], uh1[36];
#pragma unroll
    for (int c = 0; c < 36; ++c) {
        int cap = gu * 36 + c;
        const float4* W4 = (const float4*)(Wc + ((size_t)cap * 512) + l * 8);
        float4 A  = W4[0];
        float4 Bv = W4[1];
        float t0 = A.x * ub0[c * 8 + 0];
        t0 = fmaf(A.y,  ub0[c * 8 + 1], t0);
        t0 = fmaf(A.z,  ub0[c * 8 + 2], t0);
        t0 = fmaf(A.w,  ub0[c * 8 + 3], t0);
        t0 = fmaf(Bv.x, ub0[c * 8 + 4], t0);
        t0 = fmaf(Bv.y, ub0[c * 8 + 5], t0);
        t0 = fmaf(Bv.z, ub0[c * 8 + 6], t0);
        t0 = fmaf(Bv.w, ub0[c * 8 + 7], t0);
        uh0[c] = t0;
        float t1 = A.x * ub1[c * 8 + 0];
        t1 = fmaf(A.y,  ub1[c * 8 + 1], t1);
        t1 = fmaf(A.z,  ub1[c * 8 + 2], t1);
        t1 = fmaf(A.w,  ub1[c * 8 + 3], t1);
        t1 = fmaf(Bv.x, ub1[c * 8 + 4], t1);
        t1 = fmaf(Bv.y, ub1[c * 8 + 5], t1);
        t1 = fmaf(Bv.z, ub1[c * 8 + 6], t1);
        t1 = fmaf(Bv.w, ub1[c * 8 + 7], t1);
        uh1[c] = t1;
    }

    for (int r = 0; r < 3; ++r) {
        if (r > 0) {
            __builtin_amdgcn_wave_barrier();
            for (int i = l; i < 72; i += 64) {
                int bb = (i >= 36) ? 1 : 0;
                int cl = i - bb * 36;
                int c  = gu * 36 + cl;
                float4 bv = *(const float4*)&b_lds[bb][c * 4];
                float m  = fmaxf(fmaxf(bv.x, bv.y), fmaxf(bv.z, bv.w));
                float e0 = expf(bv.x - m), e1 = expf(bv.y - m);
                float e2 = expf(bv.z - m), e3 = expf(bv.w - m);
                float inv = 1.f / (e0 + e1 + e2 + e3);
                e0 *= inv; e1 *= inv; e2 *= inv; e3 *= inv;
                *(float4*)&c_lds[bb][c * 4] = make_float4(e0, e1, e2, e3);
                if (r == 2) {
                    *(float4*)(out + 16384 + ((size_t)(b0 + bb) * NCAPS + c) * 4) =
                        make_float4(e0, e1, e2, e3);
                }
            }
            __builtin_amdgcn_wave_barrier();
        }

        float p0 = 0.f, p1 = 0.f;
        if (r == 0) {
#pragma unroll
            for (int c = 0; c < 36; ++c) {
                p0 = fmaf(0.25f, uh0[c], p0);
                p1 = fmaf(0.25f, uh1[c], p1);
            }
        } else {
#pragma unroll
            for (int c = 0; c < 36; ++c) {
                p0 = fmaf(c_lds[0][(g * 36 + c) * 4 + d], uh0[c], p0);
                p1 = fmaf(c_lds[1][(g * 36 + c) * 4 + d], uh1[c], p1);
            }
        }
        part_lds[0][tid] = p0;
        part_lds[1][tid] = p1;
        __syncthreads();

        if (tid < 128) {
            int bb = tid >> 6;
            int ll = tid & 63;
            float sv = 0.f;
#pragma unroll
            for (int k = 0; k < 8; ++k) sv += part_lds[bb][ll + 64 * k];
            float sq = rowsum16(sv * sv);
            float sc = sq / (1.f + sq) / sqrtf(sq + 1e-8f);
            float v  = sv * sc;
            v_lds[bb][ll] = v;
            if (r == 2) {
                float vv = rowsum16(v * v);
                if ((ll & 15) == 0)
                    out[(size_t)(b0 + bb) * 4 + (ll >> 4)] = sqrtf(vv);
            }
        }
        __syncthreads();

        if (r < 2) {
            float v0 = v_lds[0][l];
            float v1 = v_lds[1][l];
#pragma unroll
            for (int c = 0; c < 36; ++c) {
                float t0 = rowsum16(uh0[c] * v0);
                float t1 = rowsum16(uh1[c] * v1);
                if (o == 0) {
                    if (r == 0) {
                        b_lds[0][(g * 36 + c) * 4 + d] = t0;
                        b_lds[1][(g * 36 + c) * 4 + d] = t1;
                    } else {
                        b_lds[0][(g * 36 + c) * 4 + d] += t0;
                        b_lds[1][(g * 36 + c) * 4 + d] += t1;
                    }
                }
            }
        }
    }
}

extern "C" void kernel_launch(void* const* d_in, const int* in_sizes, int n_in,
                              void* d_out, int out_size, void* d_ws, size_t ws_size,
                              hipStream_t stream) {
    const float* x      = (const float*)d_in[0];
    const float* a      = (const float*)d_in[1];
    const float* w      = (const float*)d_in[2];
    const float* conv_w = (const float*)d_in[3];
    const float* conv_b = (const float*)d_in[4];
    const float* W_caps = (const float*)d_in[5];
    float* out = (float*)d_out;
    char* ws   = (char*)d_ws;

    __hip_bfloat16*  bwh  = (__hip_bfloat16*)(ws + BWH_OFF);
    __hip_bfloat16*  bwl  = (__hip_bfloat16*)(ws + BWL_OFF);
    __hip_bfloat16*  bph  = (__hip_bfloat16*)(ws + BPH_OFF);
    __hip_bfloat16*  bpl  = (__hip_bfloat16*)(ws + BPL_OFF);
    __hip_bfloat16*  h2hi = (__hip_bfloat16*)(ws + H2HI_OFF);
    __hip_bfloat16*  h2lo = (__hip_bfloat16*)(ws + H2LO_OFF);
    float*           u    = (float*)(ws + U_OFF);

    k_wav_pack<<<256, 256, 0, stream>>>(a, w, bwh, bwl);
    k_pack_b<<<2048, 256, 0, stream>>>(conv_w, bph, bpl);
    k_wavconv_mfma<<<BATCH / 8, 256, 0, stream>>>(x, bwh, bwl, h2hi, h2lo);
    k_conv_mfma<<<(BATCH / 16) * 2, 512, 0, stream>>>(h2hi, h2lo, bph, bpl, conv_b, u);
    k_routing<<<BATCH / 2, 512, 0, stream>>>(u, W_caps, out);
}

// Round 12
// 267.393 us; speedup vs baseline: 14.1636x; 1.2999x over previous
//
#include <hip/hip_runtime.h>
#include <hip/hip_bf16.h>
#include <math.h>

typedef __attribute__((ext_vector_type(4))) short short4v;
typedef __attribute__((ext_vector_type(8))) short short8;
typedef __attribute__((ext_vector_type(4))) float f32x4;
typedef _Float16 half8 __attribute__((ext_vector_type(8)));

#define BATCH   4096
#define XLEN    1008
#define NOC1    128
#define NPOS    32
#define NOC2    256
#define NQ      9
#define NCAPS   288
#define NDIM    8

// ws layout (bytes) — all conv operands now single fp16
#define BWH_OFF   0           // wavelet B-pack fp16, 128 KB
#define BPH_OFF   131072      // conv2 B-pack fp16, 1 MB
#define H2_OFF    1179648     // h2 fp16 [b][pos32][ic128], 33.55 MB
#define U_OFF     34734080    // u fp32 [b][288][8], 37.75 MB

static __device__ __forceinline__ short f2h(float v) {
    _Float16 h = (_Float16)v;
    return *reinterpret_cast<short*>(&h);
}

// DPP 16-lane (row) sum — VALU pipe, no LDS. Bitwise == shfl_xor 1/2/4/8 tree.
template <int CTRL>
static __device__ __forceinline__ float dpp_addf(float x) {
    int y = __builtin_amdgcn_update_dpp(0, __builtin_bit_cast(int, x),
                                        CTRL, 0xf, 0xf, true);
    return x + __builtin_bit_cast(float, y);
}
static __device__ __forceinline__ float rowsum16(float x) {
    x = dpp_addf<0xB1>(x);    // quad_perm xor1
    x = dpp_addf<0x4E>(x);    // quad_perm xor2
    x = dpp_addf<0x141>(x);   // row_half_mirror
    x = dpp_addf<0x140>(x);   // row_mirror
    return x;
}

// ---------------- K1a: wavelet weights directly in MFMA B-fragment order ---
__global__ __launch_bounds__(256) void k_wav_pack(const float* __restrict__ a,
                                                  const float* __restrict__ w,
                                                  short* __restrict__ bh) {
    int idx = blockIdx.x * 256 + threadIdx.x;   // 65536 total
    int e    = idx & 7;
    int lane = (idx >> 3) & 63;
    int s    = (idx >> 9) & 15;
    int nt   = idx >> 13;
    int oc = nt * 16 + (lane & 15);
    int k  = s * 32 + (lane >> 4) * 8 + e;
    float t  = -1.0f + 2.0f * (float)k / 511.0f;
    float av = fmaxf(a[oc], 1e-5f);
    float ts = t / av;
    float v = cosf(w[oc] * t) * expf(-0.5f * ts * ts);
    bh[idx] = f2h(v);
}

// ---------------- K1b: pack conv_w into MFMA B-fragment order, fp16 --------
__global__ __launch_bounds__(256) void k_pack_b(const float* __restrict__ cw,
                                                short* __restrict__ bh) {
    int o = blockIdx.x * 256 + threadIdx.x;   // 524288 total
    int e    = o & 7;
    int lane = (o >> 3) & 63;
    int s    = (o >> 9) & 63;
    int nt   = o >> 15;
    int n  = nt * 16 + (lane & 15);
    int j  = lane >> 4;
    int kk = s >> 2;
    int ic = (s & 3) * 32 + j * 8 + e;
    bh[o] = f2h(cw[(n * NOC1 + ic) * 16 + kk]);
}

// ---------------- K2: WavConv via single fp16 MFMA -------------------------
// Block: 8 batches, 256 threads (4 waves). Wave w: m-tiles 4w..4w+3,
// all 8 n-tiles. K=512 in 16 steps. x in LDS fp16, no K-loop barriers.
__global__ __launch_bounds__(256, 2) void k_wavconv_mfma(
        const float* __restrict__ x,
        const short* __restrict__ bwh,
        short* __restrict__ h2) {
    __shared__ short xl[8][1512];   // 24192 B; slot(i) = i + 8*(i>>4)

    int tid = threadIdx.x;
    int b0  = blockIdx.x * 8;

    for (int i4 = tid; i4 < 2016; i4 += 256) {
        int b  = i4 / 252;
        int e4 = i4 - b * 252;
        float4 v = *(const float4*)(x + (size_t)(b0 + b) * XLEN + e4 * 4);
        int i    = e4 * 4;
        int slot = i + 8 * (i >> 4);
        short4v hv;
        hv.x = f2h(v.x); hv.y = f2h(v.y); hv.z = f2h(v.z); hv.w = f2h(v.w);
        *(short4v*)&xl[b][slot] = hv;
    }
    __syncthreads();

    int lane = tid & 63;
    int w    = tid >> 6;     // 0..3
    int col  = lane & 15;
    int rg   = lane >> 4;    // 0..3

    f32x4 acc[4][8];
    f32x4 z = {0.f, 0.f, 0.f, 0.f};
#pragma unroll
    for (int tl = 0; tl < 4; ++tl)
#pragma unroll
        for (int nt = 0; nt < 8; ++nt) acc[tl][nt] = z;

    for (int s = 0; s < 16; ++s) {
        half8 Bh[8];
#pragma unroll
        for (int nt = 0; nt < 8; ++nt) {
            size_t off = ((size_t)(nt * 16 + s) * 64 + lane) * 8;
            Bh[nt] = __builtin_bit_cast(half8, *(const short8*)(bwh + off));
        }
#pragma unroll
        for (int tl = 0; tl < 4; ++tl) {
            int mt  = 4 * w + tl;
            int bl  = mt >> 1;
            int pos = (mt & 1) * 16 + col;
            int i    = (pos + 2 * s) * 16 + rg * 8;
            int slot = i + 8 * (i >> 4);
            half8 ah = __builtin_bit_cast(half8, *(const short8*)&xl[bl][slot]);
#pragma unroll
            for (int nt = 0; nt < 8; ++nt)
                acc[tl][nt] = __builtin_amdgcn_mfma_f32_16x16x32_f16(ah, Bh[nt], acc[tl][nt], 0, 0, 0);
        }
    }

    // Epilogue: C/D layout col=lane&15 (oc), row=rg*4+r (pos).
#pragma unroll
    for (int tl = 0; tl < 4; ++tl) {
        int mt = 4 * w + tl;
        int b  = b0 + (mt >> 1);
        int ph = (mt & 1) * 16;
#pragma unroll
        for (int nt = 0; nt < 8; ++nt) {
            int oc = nt * 16 + col;
#pragma unroll
            for (int r = 0; r < 4; ++r) {
                int pos = ph + rg * 4 + r;
                h2[((size_t)b * NPOS + pos) * NOC1 + oc] = f2h(acc[tl][nt][r]);
            }
        }
    }
}

// ---------------- K3: PrimaryCaps conv via single fp16 MFMA + squash -------
// Grid 512 = 256 batch-groups x 2 N-halves. Block: 16 batches x 128 oc2,
// 8 waves, wave owns n-tile ch*8+w, 9 m-tiles (144 rows = 9q x 16b).
// BK=32, 64 steps, A double-buffered with compile-time alternation.
__global__ __launch_bounds__(512, 5) void k_conv_mfma(const short* __restrict__ h2,
                                                      const short* __restrict__ bph,
                                                      const float* __restrict__ cb,
                                                      float* __restrict__ u) {
    __shared__ char smem[36864];         // 2 A-buffers (11520 B); epilogue p_lds
    short* A0 = (short*)smem;            // [144 m][stride 40]
    short* A1 = (short*)(smem + 11520);
    float* p_lds = (float*)smem;         // [8 b][1152] (36864 B)

    int tid  = threadIdx.x;
    int w    = tid >> 6;
    int lane = tid & 63;
    int col  = lane & 15;
    int rg   = lane >> 4;
    int bg   = blockIdx.x >> 1;
    int ch   = blockIdx.x & 1;
    int b0   = bg * 16;
    int nt   = ch * 8 + w;               // this wave's global n-tile

    f32x4 acc[9];
    f32x4 z = {0.f, 0.f, 0.f, 0.f};
#pragma unroll
    for (int mt = 0; mt < 9; ++mt) acc[mt] = z;

    // stage step s: 144 rows x 32 shorts (4 b128 chunks/row)
    auto stageA = [&](int s, short* dst) {
        int kk  = s >> 2;
        int icb = (s & 3) * 32;
#pragma unroll
        for (int k2 = 0; k2 < 2; ++k2) {
            int idx = tid + k2 * 512;
            if (idx < 576) {
                int m = idx >> 2;        // 0..143: b = m&15, q = m>>4
                int g = idx & 3;
                const short* src = h2 +
                    ((size_t)(b0 + (m & 15)) * NPOS + (2 * (m >> 4) + kk)) * NOC1 + icb + g * 8;
                *(short8*)&dst[m * 40 + g * 8] = *(const short8*)src;
            }
        }
    };

    auto mfmaStep = [&](int s, const short* A) {
        size_t bo = ((size_t)(nt * 64 + s) * 64 + lane) * 8;
        half8 Bh = __builtin_bit_cast(half8, *(const short8*)(bph + bo));
#pragma unroll
        for (int mt = 0; mt < 9; ++mt) {
            int aoff = (mt * 16 + col) * 40 + rg * 8;
            half8 ah = __builtin_bit_cast(half8, *(const short8*)&A[aoff]);
            acc[mt] = __builtin_amdgcn_mfma_f32_16x16x32_f16(ah, Bh, acc[mt], 0, 0, 0);
        }
    };

    stageA(0, A0);
    __syncthreads();
    for (int s = 0; s < 64; s += 2) {
        if (s + 1 < 64) stageA(s + 1, A1);   // disjoint buffer
        mfmaStep(s, A0);
        __syncthreads();
        if (s + 2 < 64) stageA(s + 2, A0);
        mfmaStep(s + 1, A1);
        __syncthreads();
    }

    // Epilogue in two 8-batch passes. C/D: n = col, row = rg*4+r = batch.
    int oc2l = w * 16 + col;                  // chunk-local oc2 (0..127)
    float bias = cb[ch * 128 + oc2l];
    for (int pp = 0; pp < 2; ++pp) {
#pragma unroll
        for (int mt = 0; mt < 9; ++mt)
#pragma unroll
            for (int r = 0; r < 4; ++r) {
                int b = rg * 4 + r;           // 0..15
                if ((b >> 3) == pp)
                    p_lds[(b & 7) * 1152 + oc2l * 9 + mt] = acc[mt][r] + bias;
            }
        __syncthreads();
        for (int idx = tid; idx < 1152; idx += 512) {   // 8 b x 144 caps
            int lb = idx / 144;
            int cl = idx - lb * 144;
            float* ppt = &p_lds[lb * 1152 + cl * 8];
            float sn = 0.f;
#pragma unroll
            for (int i = 0; i < NDIM; ++i) sn = fmaf(ppt[i], ppt[i], sn);
            float sc = sn / (1.f + sn) / sqrtf(sn + 1e-8f);
            float* ug = u + ((size_t)(b0 + pp * 8 + lb) * (NCAPS * NDIM) +
                             (ch * 144 + cl) * 8);
            float4 u0 = make_float4(ppt[0] * sc, ppt[1] * sc, ppt[2] * sc, ppt[3] * sc);
            float4 u1 = make_float4(ppt[4] * sc, ppt[5] * sc, ppt[6] * sc, ppt[7] * sc);
            ((float4*)ug)[0] = u0;
            ((float4*)ug)[1] = u1;
        }
        __syncthreads();
    }
}

// ---------------- K4: u_hat + routing, 2 batches/block, 512 threads --------
__global__ __launch_bounds__(512, 4) void k_routing(const float* __restrict__ u,
                                                    const float* __restrict__ Wc,
                                                    float* __restrict__ out) {
    __shared__ float b_lds[2][NCAPS * 4];     // 9216 B
    __shared__ float c_lds[2][NCAPS * 4];     // 9216 B
    __shared__ float part_lds[2][512];        // 4096 B
    __shared__ float v_lds[2][64];            // 512 B

    int tid = threadIdx.x;
    int b0  = blockIdx.x * 2;

    int g = tid >> 6;
    int l = tid & 63;
    int d = l >> 4;
    int o = l & 15;
    int gu = __builtin_amdgcn_readfirstlane(g);   // wave-uniform -> s_load for u

    const float* ub0 = u + (size_t)(b0 + 0) * (NCAPS * NDIM) + gu * 36 * NDIM;
    const float* ub1 = u + (size_t)(b0 + 1) * (NCAPS * NDIM) + gu * 36 * NDIM;

    float uh0[36], uh1[36];
#pragma unroll
    for (int c = 0; c < 36; ++c) {
        int cap = gu * 36 + c;
        const float4* W4 = (const float4*)(Wc + ((size_t)cap * 512) + l * 8);
        float4 A  = W4[0];
        float4 Bv = W4[1];
        float t0 = A.x * ub0[c * 8 + 0];
        t0 = fmaf(A.y,  ub0[c * 8 + 1], t0);
        t0 = fmaf(A.z,  ub0[c * 8 + 2], t0);
        t0 = fmaf(A.w,  ub0[c * 8 + 3], t0);
        t0 = fmaf(Bv.x, ub0[c * 8 + 4], t0);
        t0 = fmaf(Bv.y, ub0[c * 8 + 5], t0);
        t0 = fmaf(Bv.z, ub0[c * 8 + 6], t0);
        t0 = fmaf(Bv.w, ub0[c * 8 + 7], t0);
        uh0[c] = t0;
        float t1 = A.x * ub1[c * 8 + 0];
        t1 = fmaf(A.y,  ub1[c * 8 + 1], t1);
        t1 = fmaf(A.z,  ub1[c * 8 + 2], t1);
        t1 = fmaf(A.w,  ub1[c * 8 + 3], t1);
        t1 = fmaf(Bv.x, ub1[c * 8 + 4], t1);
        t1 = fmaf(Bv.y, ub1[c * 8 + 5], t1);
        t1 = fmaf(Bv.z, ub1[c * 8 + 6], t1);
        t1 = fmaf(Bv.w, ub1[c * 8 + 7], t1);
        uh1[c] = t1;
    }

    for (int r = 0; r < 3; ++r) {
        if (r > 0) {
            __builtin_amdgcn_wave_barrier();
            for (int i = l; i < 72; i += 64) {
                int bb = (i >= 36) ? 1 : 0;
                int cl = i - bb * 36;
                int c  = gu * 36 + cl;
                float4 bv = *(const float4*)&b_lds[bb][c * 4];
                float m  = fmaxf(fmaxf(bv.x, bv.y), fmaxf(bv.z, bv.w));
                float e0 = expf(bv.x - m), e1 = expf(bv.y - m);
                float e2 = expf(bv.z - m), e3 = expf(bv.w - m);
                float inv = 1.f / (e0 + e1 + e2 + e3);
                e0 *= inv; e1 *= inv; e2 *= inv; e3 *= inv;
                *(float4*)&c_lds[bb][c * 4] = make_float4(e0, e1, e2, e3);
                if (r == 2) {
                    *(float4*)(out + 16384 + ((size_t)(b0 + bb) * NCAPS + c) * 4) =
                        make_float4(e0, e1, e2, e3);
                }
            }
            __builtin_amdgcn_wave_barrier();
        }

        float p0 = 0.f, p1 = 0.f;
        if (r == 0) {
#pragma unroll
            for (int c = 0; c < 36; ++c) {
                p0 = fmaf(0.25f, uh0[c], p0);
                p1 = fmaf(0.25f, uh1[c], p1);
            }
        } else {
#pragma unroll
            for (int c = 0; c < 36; ++c) {
                p0 = fmaf(c_lds[0][(g * 36 + c) * 4 + d], uh0[c], p0);
                p1 = fmaf(c_lds[1][(g * 36 + c) * 4 + d], uh1[c], p1);
            }
        }
        part_lds[0][tid] = p0;
        part_lds[1][tid] = p1;
        __syncthreads();

        if (tid < 128) {
            int bb = tid >> 6;
            int ll = tid & 63;
            float sv = 0.f;
#pragma unroll
            for (int k = 0; k < 8; ++k) sv += part_lds[bb][ll + 64 * k];
            float sq = rowsum16(sv * sv);
            float sc = sq / (1.f + sq) / sqrtf(sq + 1e-8f);
            float v  = sv * sc;
            v_lds[bb][ll] = v;
            if (r == 2) {
                float vv = rowsum16(v * v);
                if ((ll & 15) == 0)
                    out[(size_t)(b0 + bb) * 4 + (ll >> 4)] = sqrtf(vv);
            }
        }
        __syncthreads();

        if (r < 2) {
            float v0 = v_lds[0][l];
            float v1 = v_lds[1][l];
#pragma unroll
            for (int c = 0; c < 36; ++c) {
                float t0 = rowsum16(uh0[c] * v0);
                float t1 = rowsum16(uh1[c] * v1);
                if (o == 0) {
                    if (r == 0) {
                        b_lds[0][(g * 36 + c) * 4 + d] = t0;
                        b_lds[1][(g * 36 + c) * 4 + d] = t1;
                    } else {
                        b_lds[0][(g * 36 + c) * 4 + d] += t0;
                        b_lds[1][(g * 36 + c) * 4 + d] += t1;
                    }
                }
            }
        }
    }
}

extern "C" void kernel_launch(void* const* d_in, const int* in_sizes, int n_in,
                              void* d_out, int out_size, void* d_ws, size_t ws_size,
                              hipStream_t stream) {
    const float* x      = (const float*)d_in[0];
    const float* a      = (const float*)d_in[1];
    const float* w      = (const float*)d_in[2];
    const float* conv_w = (const float*)d_in[3];
    const float* conv_b = (const float*)d_in[4];
    const float* W_caps = (const float*)d_in[5];
    float* out = (float*)d_out;
    char* ws   = (char*)d_ws;

    short*  bwh = (short*)(ws + BWH_OFF);
    short*  bph = (short*)(ws + BPH_OFF);
    short*  h2  = (short*)(ws + H2_OFF);
    float*  u   = (float*)(ws + U_OFF);

    k_wav_pack<<<256, 256, 0, stream>>>(a, w, bwh);
    k_pack_b<<<2048, 256, 0, stream>>>(conv_w, bph);
    k_wavconv_mfma<<<BATCH / 8, 256, 0, stream>>>(x, bwh, h2);
    k_conv_mfma<<<(BATCH / 16) * 2, 512, 0, stream>>>(h2, bph, conv_b, u);
    k_routing<<<BATCH / 2, 512, 0, stream>>>(u, W_caps, out);
}

// Round 13
// 239.817 us; speedup vs baseline: 15.7922x; 1.1150x over previous
//
#include <hip/hip_runtime.h>
#include <hip/hip_bf16.h>
#include <math.h>

typedef __attribute__((ext_vector_type(4))) short short4v;
typedef __attribute__((ext_vector_type(8))) short short8;
typedef __attribute__((ext_vector_type(4))) float f32x4;
typedef _Float16 half8 __attribute__((ext_vector_type(8)));

#define BATCH   4096
#define XLEN    1008
#define NOC1    128
#define NPOS    32
#define NOC2    256
#define NQ      9
#define NCAPS   288
#define NDIM    8

// ws layout (bytes)
#define BWH_OFF   0           // wavelet B-pack fp16, 128 KB
#define BPH_OFF   131072      // conv2 B-pack fp16, 1 MB
#define H2_OFF    1179648     // h2 fp16 [b][pos32][ic128], 33.55 MB
#define U_OFF     34734080    // u fp32 [b][288][8], 37.75 MB

static __device__ __forceinline__ short f2h(float v) {
    _Float16 h = (_Float16)v;
    return *reinterpret_cast<short*>(&h);
}

// DPP 16-lane (row) sum — VALU pipe. Bitwise == shfl_xor 1/2/4/8 tree.
template <int CTRL>
static __device__ __forceinline__ float dpp_addf(float x) {
    int y = __builtin_amdgcn_update_dpp(0, __builtin_bit_cast(int, x),
                                        CTRL, 0xf, 0xf, true);
    return x + __builtin_bit_cast(float, y);
}
static __device__ __forceinline__ float rowsum16(float x) {
    x = dpp_addf<0xB1>(x);    // quad_perm xor1
    x = dpp_addf<0x4E>(x);    // quad_perm xor2
    x = dpp_addf<0x141>(x);   // row_half_mirror
    x = dpp_addf<0x140>(x);   // row_mirror
    return x;
}

// ---------------- K1: fused weight packing (wavelet + conv2), fp16 ---------
__global__ __launch_bounds__(256) void k_pack(const float* __restrict__ a,
                                              const float* __restrict__ w,
                                              const float* __restrict__ cw,
                                              short* __restrict__ bwh,
                                              short* __restrict__ bph) {
    int bid = blockIdx.x;
    int tid = threadIdx.x;
    if (bid < 256) {
        int idx = bid * 256 + tid;            // 65536 wavelet elems
        int e    = idx & 7;
        int lane = (idx >> 3) & 63;
        int s    = (idx >> 9) & 15;
        int nt   = idx >> 13;
        int oc = nt * 16 + (lane & 15);
        int k  = s * 32 + (lane >> 4) * 8 + e;
        float t  = -1.0f + 2.0f * (float)k / 511.0f;
        float av = fmaxf(a[oc], 1e-5f);
        float ts = t / av;
        bwh[idx] = f2h(cosf(w[oc] * t) * expf(-0.5f * ts * ts));
    } else {
        int o = (bid - 256) * 256 + tid;      // 524288 conv2 elems
        int e    = o & 7;
        int lane = (o >> 3) & 63;
        int s    = (o >> 9) & 63;
        int nt   = o >> 15;
        int n  = nt * 16 + (lane & 15);
        int j  = lane >> 4;
        int kk = s >> 2;
        int ic = (s & 3) * 32 + j * 8 + e;
        bph[o] = f2h(cw[(n * NOC1 + ic) * 16 + kk]);
    }
}

// ---------------- K2: WavConv via single fp16 MFMA -------------------------
__global__ __launch_bounds__(256, 2) void k_wavconv_mfma(
        const float* __restrict__ x,
        const short* __restrict__ bwh,
        short* __restrict__ h2) {
    __shared__ short xl[8][1512];   // 24192 B; slot(i) = i + 8*(i>>4)

    int tid = threadIdx.x;
    int b0  = blockIdx.x * 8;

    for (int i4 = tid; i4 < 2016; i4 += 256) {
        int b  = i4 / 252;
        int e4 = i4 - b * 252;
        float4 v = *(const float4*)(x + (size_t)(b0 + b) * XLEN + e4 * 4);
        int i    = e4 * 4;
        int slot = i + 8 * (i >> 4);
        short4v hv;
        hv.x = f2h(v.x); hv.y = f2h(v.y); hv.z = f2h(v.z); hv.w = f2h(v.w);
        *(short4v*)&xl[b][slot] = hv;
    }
    __syncthreads();

    int lane = tid & 63;
    int w    = tid >> 6;     // 0..3
    int col  = lane & 15;
    int rg   = lane >> 4;    // 0..3

    f32x4 acc[4][8];
    f32x4 z = {0.f, 0.f, 0.f, 0.f};
#pragma unroll
    for (int tl = 0; tl < 4; ++tl)
#pragma unroll
        for (int nt = 0; nt < 8; ++nt) acc[tl][nt] = z;

    for (int s = 0; s < 16; ++s) {
        half8 Bh[8];
#pragma unroll
        for (int nt = 0; nt < 8; ++nt) {
            size_t off = ((size_t)(nt * 16 + s) * 64 + lane) * 8;
            Bh[nt] = __builtin_bit_cast(half8, *(const short8*)(bwh + off));
        }
#pragma unroll
        for (int tl = 0; tl < 4; ++tl) {
            int mt  = 4 * w + tl;
            int bl  = mt >> 1;
            int pos = (mt & 1) * 16 + col;
            int i    = (pos + 2 * s) * 16 + rg * 8;
            int slot = i + 8 * (i >> 4);
            half8 ah = __builtin_bit_cast(half8, *(const short8*)&xl[bl][slot]);
#pragma unroll
            for (int nt = 0; nt < 8; ++nt)
                acc[tl][nt] = __builtin_amdgcn_mfma_f32_16x16x32_f16(ah, Bh[nt], acc[tl][nt], 0, 0, 0);
        }
    }

#pragma unroll
    for (int tl = 0; tl < 4; ++tl) {
        int mt = 4 * w + tl;
        int b  = b0 + (mt >> 1);
        int ph = (mt & 1) * 16;
#pragma unroll
        for (int nt = 0; nt < 8; ++nt) {
            int oc = nt * 16 + col;
#pragma unroll
            for (int r = 0; r < 4; ++r) {
                int pos = ph + rg * 4 + r;
                h2[((size_t)b * NPOS + pos) * NOC1 + oc] = f2h(acc[tl][nt][r]);
            }
        }
    }
}

// ---------------- K3: PrimaryCaps conv, full-N, fp16 MFMA + squash ---------
// Grid 512 (2 blocks/CU). Block: 8 batches x 256 oc2, 512 threads, 8 waves.
// Wave w owns n-tiles {w, 8+w}; M = 72 rows (m = q*8+b) in 5 padded m-tiles.
// A-fragment reads amortized over both n-tiles: 10 MFMA per 5 ds_read_b128.
// BK=32, 64 steps, double-buffered with compile-time alternation.
__global__ __launch_bounds__(512, 4) void k_conv_mfma(const short* __restrict__ h2,
                                                      const short* __restrict__ bph,
                                                      const float* __restrict__ cb,
                                                      float* __restrict__ u) {
    __shared__ char smem[36864];         // 2 A-buffers (6400 B each); p_lds epilogue
    short* A0 = (short*)smem;            // [80 rows][stride 40]
    short* A1 = (short*)(smem + 6400);
    float* p_lds = (float*)smem;         // [8 b][1152]

    int tid  = threadIdx.x;
    int w    = tid >> 6;
    int lane = tid & 63;
    int col  = lane & 15;
    int rg   = lane >> 4;
    int b0   = blockIdx.x * 8;

    f32x4 acc[5][2];
    f32x4 z = {0.f, 0.f, 0.f, 0.f};
#pragma unroll
    for (int mt = 0; mt < 5; ++mt) { acc[mt][0] = z; acc[mt][1] = z; }

    // stage step s: 72 rows x 32 shorts (4 b128 chunks/row) = 288 tasks
    auto stageA = [&](int s, short* dst) {
        int kk  = s >> 2;
        int icb = (s & 3) * 32;
        if (tid < 288) {
            int m = tid >> 2;            // 0..71: b = m&7, q = m>>3
            int g = tid & 3;
            const short* src = h2 +
                ((size_t)(b0 + (m & 7)) * NPOS + (2 * (m >> 3) + kk)) * NOC1 + icb + g * 8;
            *(short8*)&dst[m * 40 + g * 8] = *(const short8*)src;
        }
    };

    auto mfmaStep = [&](int s, const short* A) {
        short8 arow[5];
#pragma unroll
        for (int mt = 0; mt < 5; ++mt)
            arow[mt] = *(const short8*)&A[(mt * 16 + col) * 40 + rg * 8];
#pragma unroll
        for (int n = 0; n < 2; ++n) {
            size_t bo = ((size_t)((w + n * 8) * 64 + s) * 64 + lane) * 8;
            half8 Bh = __builtin_bit_cast(half8, *(const short8*)(bph + bo));
#pragma unroll
            for (int mt = 0; mt < 5; ++mt)
                acc[mt][n] = __builtin_amdgcn_mfma_f32_16x16x32_f16(
                    __builtin_bit_cast(half8, arow[mt]), Bh, acc[mt][n], 0, 0, 0);
        }
    };

    stageA(0, A0);
    __syncthreads();
    for (int s = 0; s < 64; s += 2) {
        if (s + 1 < 64) stageA(s + 1, A1);   // disjoint buffer
        mfmaStep(s, A0);
        __syncthreads();
        if (s + 2 < 64) stageA(s + 2, A0);
        mfmaStep(s + 1, A1);
        __syncthreads();
    }

    // Epilogue: two n-passes, 8 batches each. C/D: n=col, row = rg*4+r.
    int oc2l = w * 16 + col;                  // 0..127 within half
    for (int n = 0; n < 2; ++n) {
        float bias = cb[n * 128 + oc2l];
#pragma unroll
        for (int mt = 0; mt < 5; ++mt)
#pragma unroll
            for (int r = 0; r < 4; ++r) {
                int m = mt * 16 + rg * 4 + r;
                if (m < 72)
                    p_lds[(m & 7) * 1152 + oc2l * 9 + (m >> 3)] = acc[mt][n][r] + bias;
            }
        __syncthreads();
        for (int idx = tid; idx < 1152; idx += 512) {   // 8 b x 144 caps
            int lb = idx / 144;
            int cl = idx - lb * 144;
            float* ppt = &p_lds[lb * 1152 + cl * 8];
            float sn = 0.f;
#pragma unroll
            for (int i = 0; i < NDIM; ++i) sn = fmaf(ppt[i], ppt[i], sn);
            float sc = sn / (1.f + sn) / sqrtf(sn + 1e-8f);
            float* ug = u + ((size_t)(b0 + lb) * (NCAPS * NDIM) + (n * 144 + cl) * 8);
            float4 u0 = make_float4(ppt[0] * sc, ppt[1] * sc, ppt[2] * sc, ppt[3] * sc);
            float4 u1 = make_float4(ppt[4] * sc, ppt[5] * sc, ppt[6] * sc, ppt[7] * sc);
            ((float4*)ug)[0] = u0;
            ((float4*)ug)[1] = u1;
        }
        __syncthreads();
    }
}

// ---------------- K4: u_hat + routing, 2 batches/block, 512 threads --------
// u_hat W loads software-pipelined in 2-cap chunks (compile-time dbuf).
__global__ __launch_bounds__(512, 3) void k_routing(const float* __restrict__ u,
                                                    const float* __restrict__ Wc,
                                                    float* __restrict__ out) {
    __shared__ float b_lds[2][NCAPS * 4];     // 9216 B
    __shared__ float c_lds[2][NCAPS * 4];     // 9216 B
    __shared__ float part_lds[2][512];        // 4096 B
    __shared__ float v_lds[2][64];            // 512 B

    int tid = threadIdx.x;
    int b0  = blockIdx.x * 2;

    int g = tid >> 6;
    int l = tid & 63;
    int d = l >> 4;
    int o = l & 15;
    int gu = __builtin_amdgcn_readfirstlane(g);   // wave-uniform -> s_load for u

    const float* ub0 = u + (size_t)(b0 + 0) * (NCAPS * NDIM) + gu * 36 * NDIM;
    const float* ub1 = u + (size_t)(b0 + 1) * (NCAPS * NDIM) + gu * 36 * NDIM;

    float uh0[36], uh1[36];
    {
        float4 WA[2][2], WB[2][2];
        auto loadW = [&](int base, float4 (*W)[2]) {
#pragma unroll
            for (int j = 0; j < 2; ++j) {
                const float4* W4 = (const float4*)(Wc +
                    ((size_t)(gu * 36 + base + j) * 512) + l * 8);
                W[j][0] = W4[0];
                W[j][1] = W4[1];
            }
        };
        auto computeC = [&](int base, float4 (*W)[2]) {
#pragma unroll
            for (int j = 0; j < 2; ++j) {
                int c = base + j;
                float4 A  = W[j][0];
                float4 Bv = W[j][1];
                float t0 = A.x * ub0[c * 8 + 0];
                t0 = fmaf(A.y,  ub0[c * 8 + 1], t0);
                t0 = fmaf(A.z,  ub0[c * 8 + 2], t0);
                t0 = fmaf(A.w,  ub0[c * 8 + 3], t0);
                t0 = fmaf(Bv.x, ub0[c * 8 + 4], t0);
                t0 = fmaf(Bv.y, ub0[c * 8 + 5], t0);
                t0 = fmaf(Bv.z, ub0[c * 8 + 6], t0);
                t0 = fmaf(Bv.w, ub0[c * 8 + 7], t0);
                uh0[c] = t0;
                float t1 = A.x * ub1[c * 8 + 0];
                t1 = fmaf(A.y,  ub1[c * 8 + 1], t1);
                t1 = fmaf(A.z,  ub1[c * 8 + 2], t1);
                t1 = fmaf(A.w,  ub1[c * 8 + 3], t1);
                t1 = fmaf(Bv.x, ub1[c * 8 + 4], t1);
                t1 = fmaf(Bv.y, ub1[c * 8 + 5], t1);
                t1 = fmaf(Bv.z, ub1[c * 8 + 6], t1);
                t1 = fmaf(Bv.w, ub1[c * 8 + 7], t1);
                uh1[c] = t1;
            }
        };
        loadW(0, WA);
#pragma unroll
        for (int cc = 0; cc < 18; cc += 2) {
            if (cc + 1 < 18) loadW((cc + 1) * 2, WB);
            computeC(cc * 2, WA);
            if (cc + 2 < 18) loadW((cc + 2) * 2, WA);
            if (cc + 1 < 18) computeC((cc + 1) * 2, WB);
        }
    }

    for (int r = 0; r < 3; ++r) {
        if (r > 0) {
            __builtin_amdgcn_wave_barrier();
            for (int i = l; i < 72; i += 64) {
                int bb = (i >= 36) ? 1 : 0;
                int cl = i - bb * 36;
                int c  = gu * 36 + cl;
                float4 bv = *(const float4*)&b_lds[bb][c * 4];
                float m  = fmaxf(fmaxf(bv.x, bv.y), fmaxf(bv.z, bv.w));
                float e0 = expf(bv.x - m), e1 = expf(bv.y - m);
                float e2 = expf(bv.z - m), e3 = expf(bv.w - m);
                float inv = 1.f / (e0 + e1 + e2 + e3);
                e0 *= inv; e1 *= inv; e2 *= inv; e3 *= inv;
                *(float4*)&c_lds[bb][c * 4] = make_float4(e0, e1, e2, e3);
                if (r == 2) {
                    *(float4*)(out + 16384 + ((size_t)(b0 + bb) * NCAPS + c) * 4) =
                        make_float4(e0, e1, e2, e3);
                }
            }
            __builtin_amdgcn_wave_barrier();
        }

        float p0 = 0.f, p1 = 0.f;
        if (r == 0) {
#pragma unroll
            for (int c = 0; c < 36; ++c) {
                p0 = fmaf(0.25f, uh0[c], p0);
                p1 = fmaf(0.25f, uh1[c], p1);
            }
        } else {
#pragma unroll
            for (int c = 0; c < 36; ++c) {
                p0 = fmaf(c_lds[0][(g * 36 + c) * 4 + d], uh0[c], p0);
                p1 = fmaf(c_lds[1][(g * 36 + c) * 4 + d], uh1[c], p1);
            }
        }
        part_lds[0][tid] = p0;
        part_lds[1][tid] = p1;
        __syncthreads();

        if (tid < 128) {
            int bb = tid >> 6;
            int ll = tid & 63;
            float sv = 0.f;
#pragma unroll
            for (int k = 0; k < 8; ++k) sv += part_lds[bb][ll + 64 * k];
            float sq = rowsum16(sv * sv);
            float sc = sq / (1.f + sq) / sqrtf(sq + 1e-8f);
            float v  = sv * sc;
            v_lds[bb][ll] = v;
            if (r == 2) {
                float vv = rowsum16(v * v);
                if ((ll & 15) == 0)
                    out[(size_t)(b0 + bb) * 4 + (ll >> 4)] = sqrtf(vv);
            }
        }
        __syncthreads();

        if (r < 2) {
            float v0 = v_lds[0][l];
            float v1 = v_lds[1][l];
#pragma unroll
            for (int c = 0; c < 36; ++c) {
                float t0 = rowsum16(uh0[c] * v0);
                float t1 = rowsum16(uh1[c] * v1);
                if (o == 0) {
                    if (r == 0) {
                        b_lds[0][(g * 36 + c) * 4 + d] = t0;
                        b_lds[1][(g * 36 + c) * 4 + d] = t1;
                    } else {
                        b_lds[0][(g * 36 + c) * 4 + d] += t0;
                        b_lds[1][(g * 36 + c) * 4 + d] += t1;
                    }
                }
            }
        }
    }
}

extern "C" void kernel_launch(void* const* d_in, const int* in_sizes, int n_in,
                              void* d_out, int out_size, void* d_ws, size_t ws_size,
                              hipStream_t stream) {
    const float* x      = (const float*)d_in[0];
    const float* a      = (const float*)d_in[1];
    const float* w      = (const float*)d_in[2];
    const float* conv_w = (const float*)d_in[3];
    const float* conv_b = (const float*)d_in[4];
    const float* W_caps = (const float*)d_in[5];
    float* out = (float*)d_out;
    char* ws   = (char*)d_ws;

    short*  bwh = (short*)(ws + BWH_OFF);
    short*  bph = (short*)(ws + BPH_OFF);
    short*  h2  = (short*)(ws + H2_OFF);
    float*  u   = (float*)(ws + U_OFF);

    k_pack<<<2304, 256, 0, stream>>>(a, w, conv_w, bwh, bph);
    k_wavconv_mfma<<<BATCH / 8, 256, 0, stream>>>(x, bwh, h2);
    k_conv_mfma<<<BATCH / 8, 512, 0, stream>>>(h2, bph, conv_b, u);
    k_routing<<<BATCH / 2, 512, 0, stream>>>(u, W_caps, out);
}

// Round 14
// 238.086 us; speedup vs baseline: 15.9070x; 1.0073x over previous
//
#include <hip/hip_runtime.h>
#include <hip/hip_bf16.h>
#include <math.h>

typedef __attribute__((ext_vector_type(4))) short short4v;
typedef __attribute__((ext_vector_type(8))) short short8;
typedef __attribute__((ext_vector_type(4))) float f32x4;
typedef __attribute__((ext_vector_type(2))) float f32x2;
typedef _Float16 half8 __attribute__((ext_vector_type(8)));

#define BATCH   4096
#define XLEN    1008
#define NOC1    128
#define NPOS    32
#define NOC2    256
#define NQ      9
#define NCAPS   288
#define NDIM    8

// ws layout (bytes)
#define BWH_OFF   0           // wavelet B-pack fp16, 128 KB
#define BPH_OFF   131072      // conv2 B-pack fp16, 1 MB
#define H2_OFF    1179648     // h2 fp16 [b][pos32][ic128], 33.55 MB
#define U_OFF     34734080    // u fp32 [b][288][8], 37.75 MB

static __device__ __forceinline__ short f2h(float v) {
    _Float16 h = (_Float16)v;
    return *reinterpret_cast<short*>(&h);
}

// packed fp32 fma on batch-pairs: a (splat) * b + c  ->  v_pk_fma_f32
static __device__ __forceinline__ f32x2 pkfma(float a, f32x2 b, f32x2 c) {
    f32x2 av = {a, a};
    return av * b + c;    // clang: llvm.fmuladd<2 x float> -> v_pk_fma_f32
}

// DPP 16-lane (row) sum — VALU pipe. Bitwise == shfl_xor 1/2/4/8 tree.
template <int CTRL>
static __device__ __forceinline__ float dpp_addf(float x) {
    int y = __builtin_amdgcn_update_dpp(0, __builtin_bit_cast(int, x),
                                        CTRL, 0xf, 0xf, true);
    return x + __builtin_bit_cast(float, y);
}
static __device__ __forceinline__ float rowsum16(float x) {
    x = dpp_addf<0xB1>(x);    // quad_perm xor1
    x = dpp_addf<0x4E>(x);    // quad_perm xor2
    x = dpp_addf<0x141>(x);   // row_half_mirror
    x = dpp_addf<0x140>(x);   // row_mirror
    return x;
}

// ---------------- K1: fused weight packing (wavelet + conv2), fp16 ---------
__global__ __launch_bounds__(256) void k_pack(const float* __restrict__ a,
                                              const float* __restrict__ w,
                                              const float* __restrict__ cw,
                                              short* __restrict__ bwh,
                                              short* __restrict__ bph) {
    int bid = blockIdx.x;
    int tid = threadIdx.x;
    if (bid < 256) {
        int idx = bid * 256 + tid;            // 65536 wavelet elems
        int e    = idx & 7;
        int lane = (idx >> 3) & 63;
        int s    = (idx >> 9) & 15;
        int nt   = idx >> 13;
        int oc = nt * 16 + (lane & 15);
        int k  = s * 32 + (lane >> 4) * 8 + e;
        float t  = -1.0f + 2.0f * (float)k / 511.0f;
        float av = fmaxf(a[oc], 1e-5f);
        float ts = t / av;
        bwh[idx] = f2h(cosf(w[oc] * t) * expf(-0.5f * ts * ts));
    } else {
        int o = (bid - 256) * 256 + tid;      // 524288 conv2 elems
        int e    = o & 7;
        int lane = (o >> 3) & 63;
        int s    = (o >> 9) & 63;
        int nt   = o >> 15;
        int n  = nt * 16 + (lane & 15);
        int j  = lane >> 4;
        int kk = s >> 2;
        int ic = (s & 3) * 32 + j * 8 + e;
        bph[o] = f2h(cw[(n * NOC1 + ic) * 16 + kk]);
    }
}

// ---------------- K2: WavConv via single fp16 MFMA -------------------------
__global__ __launch_bounds__(256, 2) void k_wavconv_mfma(
        const float* __restrict__ x,
        const short* __restrict__ bwh,
        short* __restrict__ h2) {
    __shared__ short xl[8][1512];   // 24192 B; slot(i) = i + 8*(i>>4)

    int tid = threadIdx.x;
    int b0  = blockIdx.x * 8;

    for (int i4 = tid; i4 < 2016; i4 += 256) {
        int b  = i4 / 252;
        int e4 = i4 - b * 252;
        float4 v = *(const float4*)(x + (size_t)(b0 + b) * XLEN + e4 * 4);
        int i    = e4 * 4;
        int slot = i + 8 * (i >> 4);
        short4v hv;
        hv.x = f2h(v.x); hv.y = f2h(v.y); hv.z = f2h(v.z); hv.w = f2h(v.w);
        *(short4v*)&xl[b][slot] = hv;
    }
    __syncthreads();

    int lane = tid & 63;
    int w    = tid >> 6;     // 0..3
    int col  = lane & 15;
    int rg   = lane >> 4;    // 0..3

    f32x4 acc[4][8];
    f32x4 z = {0.f, 0.f, 0.f, 0.f};
#pragma unroll
    for (int tl = 0; tl < 4; ++tl)
#pragma unroll
        for (int nt = 0; nt < 8; ++nt) acc[tl][nt] = z;

    for (int s = 0; s < 16; ++s) {
        half8 Bh[8];
#pragma unroll
        for (int nt = 0; nt < 8; ++nt) {
            size_t off = ((size_t)(nt * 16 + s) * 64 + lane) * 8;
            Bh[nt] = __builtin_bit_cast(half8, *(const short8*)(bwh + off));
        }
#pragma unroll
        for (int tl = 0; tl < 4; ++tl) {
            int mt  = 4 * w + tl;
            int bl  = mt >> 1;
            int pos = (mt & 1) * 16 + col;
            int i    = (pos + 2 * s) * 16 + rg * 8;
            int slot = i + 8 * (i >> 4);
            half8 ah = __builtin_bit_cast(half8, *(const short8*)&xl[bl][slot]);
#pragma unroll
            for (int nt = 0; nt < 8; ++nt)
                acc[tl][nt] = __builtin_amdgcn_mfma_f32_16x16x32_f16(ah, Bh[nt], acc[tl][nt], 0, 0, 0);
        }
    }

#pragma unroll
    for (int tl = 0; tl < 4; ++tl) {
        int mt = 4 * w + tl;
        int b  = b0 + (mt >> 1);
        int ph = (mt & 1) * 16;
#pragma unroll
        for (int nt = 0; nt < 8; ++nt) {
            int oc = nt * 16 + col;
#pragma unroll
            for (int r = 0; r < 4; ++r) {
                int pos = ph + rg * 4 + r;
                h2[((size_t)b * NPOS + pos) * NOC1 + oc] = f2h(acc[tl][nt][r]);
            }
        }
    }
}

// ---------------- K3: PrimaryCaps conv, full-N, fp16 MFMA + squash ---------
__global__ __launch_bounds__(512, 4) void k_conv_mfma(const short* __restrict__ h2,
                                                      const short* __restrict__ bph,
                                                      const float* __restrict__ cb,
                                                      float* __restrict__ u) {
    __shared__ char smem[36864];         // 2 A-buffers (6400 B each); p_lds epilogue
    short* A0 = (short*)smem;            // [80 rows][stride 40]
    short* A1 = (short*)(smem + 6400);
    float* p_lds = (float*)smem;         // [8 b][1152]

    int tid  = threadIdx.x;
    int w    = tid >> 6;
    int lane = tid & 63;
    int col  = lane & 15;
    int rg   = lane >> 4;
    int b0   = blockIdx.x * 8;

    f32x4 acc[5][2];
    f32x4 z = {0.f, 0.f, 0.f, 0.f};
#pragma unroll
    for (int mt = 0; mt < 5; ++mt) { acc[mt][0] = z; acc[mt][1] = z; }

    auto stageA = [&](int s, short* dst) {
        int kk  = s >> 2;
        int icb = (s & 3) * 32;
        if (tid < 288) {
            int m = tid >> 2;            // 0..71: b = m&7, q = m>>3
            int g = tid & 3;
            const short* src = h2 +
                ((size_t)(b0 + (m & 7)) * NPOS + (2 * (m >> 3) + kk)) * NOC1 + icb + g * 8;
            *(short8*)&dst[m * 40 + g * 8] = *(const short8*)src;
        }
    };

    auto mfmaStep = [&](int s, const short* A) {
        short8 arow[5];
#pragma unroll
        for (int mt = 0; mt < 5; ++mt)
            arow[mt] = *(const short8*)&A[(mt * 16 + col) * 40 + rg * 8];
#pragma unroll
        for (int n = 0; n < 2; ++n) {
            size_t bo = ((size_t)((w + n * 8) * 64 + s) * 64 + lane) * 8;
            half8 Bh = __builtin_bit_cast(half8, *(const short8*)(bph + bo));
#pragma unroll
            for (int mt = 0; mt < 5; ++mt)
                acc[mt][n] = __builtin_amdgcn_mfma_f32_16x16x32_f16(
                    __builtin_bit_cast(half8, arow[mt]), Bh, acc[mt][n], 0, 0, 0);
        }
    };

    stageA(0, A0);
    __syncthreads();
    for (int s = 0; s < 64; s += 2) {
        if (s + 1 < 64) stageA(s + 1, A1);   // disjoint buffer
        mfmaStep(s, A0);
        __syncthreads();
        if (s + 2 < 64) stageA(s + 2, A0);
        mfmaStep(s + 1, A1);
        __syncthreads();
    }

    int oc2l = w * 16 + col;                  // 0..127 within half
    for (int n = 0; n < 2; ++n) {
        float bias = cb[n * 128 + oc2l];
#pragma unroll
        for (int mt = 0; mt < 5; ++mt)
#pragma unroll
            for (int r = 0; r < 4; ++r) {
                int m = mt * 16 + rg * 4 + r;
                if (m < 72)
                    p_lds[(m & 7) * 1152 + oc2l * 9 + (m >> 3)] = acc[mt][n][r] + bias;
            }
        __syncthreads();
        for (int idx = tid; idx < 1152; idx += 512) {   // 8 b x 144 caps
            int lb = idx / 144;
            int cl = idx - lb * 144;
            float* ppt = &p_lds[lb * 1152 + cl * 8];
            float sn = 0.f;
#pragma unroll
            for (int i = 0; i < NDIM; ++i) sn = fmaf(ppt[i], ppt[i], sn);
            float sc = sn / (1.f + sn) / sqrtf(sn + 1e-8f);
            float* ug = u + ((size_t)(b0 + lb) * (NCAPS * NDIM) + (n * 144 + cl) * 8);
            float4 u0 = make_float4(ppt[0] * sc, ppt[1] * sc, ppt[2] * sc, ppt[3] * sc);
            float4 u1 = make_float4(ppt[4] * sc, ppt[5] * sc, ppt[6] * sc, ppt[7] * sc);
            ((float4*)ug)[0] = u0;
            ((float4*)ug)[1] = u1;
        }
        __syncthreads();
    }
}

// ---------------- K4: u_hat + routing, 2 batches/block, 512 threads --------
// Batch-pair math packed as float2 -> v_pk_fma_f32 (2 fp32 FMA/instr).
// Per-element fma order unchanged -> bit-identical results.
__global__ __launch_bounds__(512, 4) void k_routing(const float* __restrict__ u,
                                                    const float* __restrict__ Wc,
                                                    float* __restrict__ out) {
    __shared__ float b_lds[2][NCAPS * 4];     // 9216 B
    __shared__ float c_lds[2][NCAPS * 4];     // 9216 B
    __shared__ float part_lds[2][512];        // 4096 B
    __shared__ float v_lds[2][64];            // 512 B

    int tid = threadIdx.x;
    int b0  = blockIdx.x * 2;

    int g = tid >> 6;
    int l = tid & 63;
    int d = l >> 4;
    int o = l & 15;
    int gu = __builtin_amdgcn_readfirstlane(g);   // wave-uniform -> s_load for u

    const float* ub0 = u + (size_t)(b0 + 0) * (NCAPS * NDIM) + gu * 36 * NDIM;
    const float* ub1 = u + (size_t)(b0 + 1) * (NCAPS * NDIM) + gu * 36 * NDIM;

    f32x2 uh[36];
#pragma unroll
    for (int c = 0; c < 36; ++c) {
        int cap = gu * 36 + c;
        const float4* W4 = (const float4*)(Wc + ((size_t)cap * 512) + l * 8);
        float4 A  = W4[0];
        float4 Bv = W4[1];
        f32x2 u0 = {ub0[c * 8 + 0], ub1[c * 8 + 0]};
        f32x2 u1 = {ub0[c * 8 + 1], ub1[c * 8 + 1]};
        f32x2 u2 = {ub0[c * 8 + 2], ub1[c * 8 + 2]};
        f32x2 u3 = {ub0[c * 8 + 3], ub1[c * 8 + 3]};
        f32x2 u4 = {ub0[c * 8 + 4], ub1[c * 8 + 4]};
        f32x2 u5 = {ub0[c * 8 + 5], ub1[c * 8 + 5]};
        f32x2 u6 = {ub0[c * 8 + 6], ub1[c * 8 + 6]};
        f32x2 u7 = {ub0[c * 8 + 7], ub1[c * 8 + 7]};
        f32x2 t = (f32x2){A.x, A.x} * u0;
        t = pkfma(A.y,  u1, t);
        t = pkfma(A.z,  u2, t);
        t = pkfma(A.w,  u3, t);
        t = pkfma(Bv.x, u4, t);
        t = pkfma(Bv.y, u5, t);
        t = pkfma(Bv.z, u6, t);
        t = pkfma(Bv.w, u7, t);
        uh[c] = t;
    }

    for (int r = 0; r < 3; ++r) {
        if (r > 0) {
            __builtin_amdgcn_wave_barrier();
            for (int i = l; i < 72; i += 64) {
                int bb = (i >= 36) ? 1 : 0;
                int cl = i - bb * 36;
                int c  = gu * 36 + cl;
                float4 bv = *(const float4*)&b_lds[bb][c * 4];
                float m  = fmaxf(fmaxf(bv.x, bv.y), fmaxf(bv.z, bv.w));
                float e0 = expf(bv.x - m), e1 = expf(bv.y - m);
                float e2 = expf(bv.z - m), e3 = expf(bv.w - m);
                float inv = 1.f / (e0 + e1 + e2 + e3);
                e0 *= inv; e1 *= inv; e2 *= inv; e3 *= inv;
                *(float4*)&c_lds[bb][c * 4] = make_float4(e0, e1, e2, e3);
                if (r == 2) {
                    *(float4*)(out + 16384 + ((size_t)(b0 + bb) * NCAPS + c) * 4) =
                        make_float4(e0, e1, e2, e3);
                }
            }
            __builtin_amdgcn_wave_barrier();
        }

        f32x2 p = {0.f, 0.f};
        if (r == 0) {
#pragma unroll
            for (int c = 0; c < 36; ++c)
                p = pkfma(0.25f, uh[c], p);
        } else {
#pragma unroll
            for (int c = 0; c < 36; ++c) {
                f32x2 c2 = {c_lds[0][(g * 36 + c) * 4 + d],
                            c_lds[1][(g * 36 + c) * 4 + d]};
                p = c2 * uh[c] + p;    // v_pk_fma_f32
            }
        }
        part_lds[0][tid] = p.x;
        part_lds[1][tid] = p.y;
        __syncthreads();

        if (tid < 128) {
            int bb = tid >> 6;
            int ll = tid & 63;
            float sv = 0.f;
#pragma unroll
            for (int k = 0; k < 8; ++k) sv += part_lds[bb][ll + 64 * k];
            float sq = rowsum16(sv * sv);
            float sc = sq / (1.f + sq) / sqrtf(sq + 1e-8f);
            float v  = sv * sc;
            v_lds[bb][ll] = v;
            if (r == 2) {
                float vv = rowsum16(v * v);
                if ((ll & 15) == 0)
                    out[(size_t)(b0 + bb) * 4 + (ll >> 4)] = sqrtf(vv);
            }
        }
        __syncthreads();

        if (r < 2) {
            f32x2 v01 = {v_lds[0][l], v_lds[1][l]};
#pragma unroll
            for (int c = 0; c < 36; ++c) {
                f32x2 t2 = uh[c] * v01;    // packed mul
                float t0 = rowsum16(t2.x);
                float t1 = rowsum16(t2.y);
                if (o == 0) {
                    if (r == 0) {
                        b_lds[0][(g * 36 + c) * 4 + d] = t0;
                        b_lds[1][(g * 36 + c) * 4 + d] = t1;
                    } else {
                        b_lds[0][(g * 36 + c) * 4 + d] += t0;
                        b_lds[1][(g * 36 + c) * 4 + d] += t1;
                    }
                }
            }
        }
    }
}

extern "C" void kernel_launch(void* const* d_in, const int* in_sizes, int n_in,
                              void* d_out, int out_size, void* d_ws, size_t ws_size,
                              hipStream_t stream) {
    const float* x      = (const float*)d_in[0];
    const float* a      = (const float*)d_in[1];
    const float* w      = (const float*)d_in[2];
    const float* conv_w = (const float*)d_in[3];
    const float* conv_b = (const float*)d_in[4];
    const float* W_caps = (const float*)d_in[5];
    float* out = (float*)d_out;
    char* ws   = (char*)d_ws;

    short*  bwh = (short*)(ws + BWH_OFF);
    short*  bph = (short*)(ws + BPH_OFF);
    short*  h2  = (short*)(ws + H2_OFF);
    float*  u   = (float*)(ws + U_OFF);

    k_pack<<<2304, 256, 0, stream>>>(a, w, conv_w, bwh, bph);
    k_wavconv_mfma<<<BATCH / 8, 256, 0, stream>>>(x, bwh, h2);
    k_conv_mfma<<<BATCH / 8, 512, 0, stream>>>(h2, bph, conv_b, u);
    k_routing<<<BATCH / 2, 512, 0, stream>>>(u, W_caps, out);
}